// Round 7
// baseline (2088.279 us; speedup 1.0000x reference)
//
#include <hip/hip_runtime.h>

#define IMH 64
#define IMW 64
#define HWSZ 4096
#define BATCH 16
#define TSTEPS 16
#define PADW 66

typedef _Float16 half8 __attribute__((ext_vector_type(8)));
typedef _Float16 half4 __attribute__((ext_vector_type(4)));
typedef float floatx4 __attribute__((ext_vector_type(4)));
typedef int intx4 __attribute__((ext_vector_type(4)));

__device__ __forceinline__ float sigmoidf_(float x) { return 1.f / (1.f + __expf(-x)); }
__device__ __forceinline__ float tanhf_(float x) { return 1.f - 2.f / (1.f + __expf(2.f * x)); }

// Dense weight repack: wr[gt][m][k32], m = (g*4+hg)*16 + i, out = g*64+hg*16+i.
// kg = chunk*32+k ; xmode: kg<64 -> ci=kg+1 (h), kg==64 -> ci=0 (x), else zero-pad.
__global__ void repack_w(const float* __restrict__ w, _Float16* __restrict__ wr,
                         int ngt, int cin, int xmode) {
    int total = ngt * 8192;
    for (int idx = blockIdx.x * blockDim.x + threadIdx.x; idx < total;
         idx += gridDim.x * blockDim.x) {
        int k = idx & 31;
        int m = (idx >> 5) & 255;
        int gt = idx >> 13;
        int chunk = gt / 9, tap = gt - chunk * 9;
        int bidx = m >> 4, i = m & 15;
        int g = bidx >> 2, hg = bidx & 3;
        int out = g * 64 + hg * 16 + i;
        int kg = chunk * 32 + k;
        int ci = xmode ? (kg < 64 ? kg + 1 : (kg == 64 ? 0 : -1))
                       : (kg < cin ? kg : -1);
        float v = (ci >= 0) ? w[(out * cin + ci) * 9 + tap] : 0.f;
        wr[idx] = (_Float16)v;
    }
}

// Fused conv3x3 -> 4 gates -> LSTM update. f16 MFMA implicit GEMM.
// Block: 256 thr (4 waves = 4 hid-groups), 2 image rows x 64 cols (N=128), M=256.
// Weights: NOT staged in LDS — A-fragments loaded per-tap straight from the
// L2-resident dense wr[gt][256][32] (per-lane contiguous 16B, wave = 4KB coalesced).
// Act: single LDS buffer, staged via plain global loads -> VGPR pf[] -> ds_write,
// under a classic two-barrier-per-chunk discipline (B1: prev readers done;
// B2: writes visible). Loads for chunk k+1 issue before chunk k's taps (hidden).
// LDS pixel stride 80B (4 data slots + 1 unwritten pad) -> bfr reads 2-way (free).
template<int NCHUNK, int XCHUNK>
__global__ __launch_bounds__(256, 2) void lstm_mfma_kernel(
    const _Float16* __restrict__ srcA,    // chunks 0-1 (padded pixel-major h)
    const _Float16* __restrict__ srcB,    // chunks 2-3
    const float* __restrict__ xsrc,       // layer0 x_t (batch stride TSTEPS*HWSZ)
    _Float16* __restrict__ hpad,          // out h [B][66][66][64]
    float* __restrict__ cpix,             // in-place c [B][4096][64]
    const _Float16* __restrict__ wr,      // [NGT][256][32] dense f16
    const float* __restrict__ bias)       // [256]
{
    __shared__ __align__(16) _Float16 act[10560];   // 264 px x 5 slots x 16B = 21.1 KB

    const int tid = threadIdx.x;
    const int lane = tid & 63;
    const int n = lane & 15, q = lane >> 4;
    const int hg = tid >> 6;                 // wave = hid group 0..3
    const int rb = blockIdx.x;               // row pair 0..31
    const int b = blockIdx.y;

    floatx4 acc[4][8];
    #pragma unroll
    for (int g = 0; g < 4; ++g)
        #pragma unroll
        for (int i = 0; i < 8; ++i) acc[g][i] = (floatx4){0.f, 0.f, 0.f, 0.f};

    intx4 pf[5];                             // staged 16B chunks for next act tile

    // issue plain global loads for chunk's act tile into pf[] (no LDS access)
    auto ld = [&](int chunk) {
        if (chunk == XCHUNK) return;         // x-chunk is VALU-generated at store
        const _Float16* buf = (chunk < 2) ? srcA : srcB;
        const int halfsel = chunk & 1;
        #pragma unroll
        for (int i = 0; i < 5; ++i) {
            int t = tid + i * 256;
            if (t < 1056) {
                int pix = t >> 2, sl = t & 3;
                int r = pix / 66, cs = pix - r * 66;
                const _Float16* g = buf
                    + ((size_t)(b * PADW + rb * 2 + r) * PADW + cs) * 64
                    + halfsel * 32 + sl * 8;
                pf[i] = *(const intx4*)g;
            }
        }
    };

    // commit pf[] (or VALU-generated x tile) to LDS
    auto st = [&](int chunk) {
        if (chunk == XCHUNK) {
            for (int t = tid; t < 1056; t += 256) {
                int pix = t >> 2, sl = t & 3;
                int r = pix / 66, cs = pix - r * 66;
                half8 hv;
                #pragma unroll
                for (int j = 0; j < 8; ++j) hv[j] = (_Float16)0.f;
                if (sl == 0) {
                    int gy = rb * 2 - 1 + r, gx = cs - 1;
                    float v = 0.f;
                    if (gy >= 0 && gy < IMH && gx >= 0 && gx < IMW)
                        v = xsrc[(size_t)b * (TSTEPS * HWSZ) + gy * IMW + gx];
                    hv[0] = (_Float16)v;
                }
                *(half8*)&act[(pix * 5 + sl) * 8] = hv;
            }
        } else {
            #pragma unroll
            for (int i = 0; i < 5; ++i) {
                int t = tid + i * 256;
                if (t < 1056) {
                    int pix = t >> 2, sl = t & 3;
                    *(intx4*)&act[(pix * 5 + sl) * 8] = pf[i];
                }
            }
        }
    };

    ld(0);

    for (int chunk = 0; chunk < NCHUNK; ++chunk) {
        __syncthreads();                     // B1: prev chunk's act readers done
        st(chunk);
        if (chunk + 1 < NCHUNK) ld(chunk + 1);
        __syncthreads();                     // B2: act writes visible to all waves
        const _Float16* wbase = wr + (size_t)(chunk * 9) * 8192 + (hg * 16 + n) * 32 + q * 8;
        #pragma unroll
        for (int tap = 0; tap < 9; ++tap) {
            half8 wfr[4];
            #pragma unroll
            for (int g = 0; g < 4; ++g)
                wfr[g] = *(const half8*)(wbase + (size_t)tap * 8192 + g * 2048);
            const int dy = tap / 3, dx = tap - dy * 3;
            half8 bfr[8];
            #pragma unroll
            for (int ni = 0; ni < 8; ++ni) {
                int row = (ni >> 2) + dy;                // 0..3
                int col = 16 * (ni & 3) + n + dx;        // 0..65
                bfr[ni] = *(const half8*)&act[(row * 330 + col * 5 + q) * 8];
            }
            #pragma unroll
            for (int g = 0; g < 4; ++g)
                #pragma unroll
                for (int ni = 0; ni < 8; ++ni)
                    acc[g][ni] = __builtin_amdgcn_mfma_f32_16x16x32_f16(
                        wfr[g], bfr[ni], acc[g][ni], 0, 0, 0);
        }
    }

    // Epilogue: lane holds gates for h = hg*16+q*4+r, pixel row rb*2+(ni>>2), col 16*(ni&3)+n
    const int hb = hg * 16 + q * 4;
    floatx4 bi = *(const floatx4*)&bias[hb];
    floatx4 bf = *(const floatx4*)&bias[64 + hb];
    floatx4 bo = *(const floatx4*)&bias[128 + hb];
    floatx4 bg = *(const floatx4*)&bias[192 + hb];
    #pragma unroll
    for (int ni = 0; ni < 8; ++ni) {
        int y = rb * 2 + (ni >> 2);
        int col = 16 * (ni & 3) + n;
        size_t cidx = ((size_t)b * HWSZ + y * IMW + col) * 64 + hb;
        floatx4 cold = *(const floatx4*)&cpix[cidx];
        floatx4 cnew;
        half4 hv;
        #pragma unroll
        for (int r = 0; r < 4; ++r) {
            float zi = acc[0][ni][r] + bi[r];
            float zf = acc[1][ni][r] + bf[r];
            float zo = acc[2][ni][r] + bo[r];
            float zg = acc[3][ni][r] + bg[r];
            float cn = fmaf(sigmoidf_(zf), cold[r], sigmoidf_(zi) * tanhf_(zg));
            cnew[r] = cn;
            hv[r] = (_Float16)(sigmoidf_(zo) * tanhf_(cn));
        }
        *(floatx4*)&cpix[cidx] = cnew;
        *(half4*)&hpad[((size_t)(b * PADW + y + 1) * PADW + col + 1) * 64 + hb] = hv;
    }
}

__global__ void head_kernel(const _Float16* __restrict__ h1pad,
                            const float* __restrict__ wh,
                            const float* __restrict__ bh,
                            float* __restrict__ out) {
    int nn = blockIdx.x * blockDim.x + threadIdx.x;  // 0..65535
    int b = nn >> 12, pp = nn & 4095;
    int y = pp >> 6, xc = pp & 63;
    const _Float16* base = h1pad + ((size_t)(b * PADW + y + 1) * PADW + xc + 1) * 64;
    float s = bh[0];
    #pragma unroll
    for (int h0 = 0; h0 < 64; h0 += 8) {
        half8 hv = *(const half8*)&base[h0];
        #pragma unroll
        for (int j = 0; j < 8; ++j) s = fmaf((float)hv[j], wh[h0 + j], s);
    }
    out[nn] = fmaxf(s, 0.f);
}

extern "C" void kernel_launch(void* const* d_in, const int* in_sizes, int n_in,
                              void* d_out, int out_size, void* d_ws, size_t ws_size,
                              hipStream_t stream) {
    const float* x  = (const float*)d_in[0];
    const float* w0 = (const float*)d_in[1];
    const float* b0 = (const float*)d_in[2];
    const float* w1 = (const float*)d_in[3];
    const float* b1 = (const float*)d_in[4];
    const float* wh = (const float*)d_in[5];
    const float* bh = (const float*)d_in[6];
    float* out = (float*)d_out;

    const size_t HPAD = (size_t)BATCH * PADW * PADW * 64;  // 4,460,544 halves
    const size_t CBUF = (size_t)BATCH * HWSZ * 64;         // 4,194,304 floats
    _Float16* hp  = (_Float16*)d_ws;
    _Float16* h0a = hp;
    _Float16* h0b = hp + HPAD;
    _Float16* h1a = hp + 2 * HPAD;
    _Float16* h1b = hp + 3 * HPAD;
    float* cbase = (float*)(hp + 4 * HPAD);
    float* c0 = cbase;
    float* c1 = cbase + CBUF;
    _Float16* wr0 = (_Float16*)(cbase + 2 * CBUF);   // 27*8192 halves
    _Float16* wr1 = wr0 + (size_t)27 * 8192;         // 36*8192 halves

    // zero h buffers (borders must stay 0) and c buffers
    hipMemsetAsync(d_ws, 0, 4 * HPAD * sizeof(_Float16) + 2 * CBUF * sizeof(float), stream);
    repack_w<<<864, 256, 0, stream>>>(w0, wr0, 27, 65, 1);
    repack_w<<<1152, 256, 0, stream>>>(w1, wr1, 36, 128, 0);

    _Float16* h0buf[2] = {h0a, h0b};
    _Float16* h1buf[2] = {h1a, h1b};
    dim3 grid(32, BATCH), block(256);                // 512 blocks = 2/CU
    for (int t = 0; t < TSTEPS; ++t) {
        int cur = t & 1, nxt = cur ^ 1;
        // layer0: chunks = [h0 ch0-31][h0 ch32-63][x + zeros]
        lstm_mfma_kernel<3, 2><<<grid, block, 0, stream>>>(
            h0buf[cur], (const _Float16*)nullptr, x + (size_t)t * HWSZ,
            h0buf[nxt], c0, wr0, b0);
        // layer1: chunks = [h0new 0-31][h0new 32-63][h1 0-31][h1 32-63]
        lstm_mfma_kernel<4, -1><<<grid, block, 0, stream>>>(
            h0buf[nxt], h1buf[cur], (const float*)nullptr,
            h1buf[nxt], c1, wr1, b1);
    }
    // t=15 wrote h1buf[0]
    head_kernel<<<256, 256, 0, stream>>>(h1buf[0], wh, bh, out);
}

// Round 8
// 1816.062 us; speedup vs baseline: 1.1499x; 1.1499x over previous
//
#include <hip/hip_runtime.h>

#define IMH 64
#define IMW 64
#define HWSZ 4096
#define BATCH 16
#define TSTEPS 16
#define PADW 66

typedef _Float16 half8 __attribute__((ext_vector_type(8)));
typedef _Float16 half4 __attribute__((ext_vector_type(4)));
typedef float floatx4 __attribute__((ext_vector_type(4)));
typedef int intx4 __attribute__((ext_vector_type(4)));

__device__ __forceinline__ float sigmoidf_(float x) { return 1.f / (1.f + __expf(-x)); }
__device__ __forceinline__ float tanhf_(float x) { return 1.f - 2.f / (1.f + __expf(2.f * x)); }

// Dense weight repack: wr[gt][m][k32], m = (g*4+hg)*16 + i, out = g*64+hg*16+i.
// kg = chunk*32+k ; xmode: kg<64 -> ci=kg+1 (h), kg==64 -> ci=0 (x), else zero-pad.
__global__ void repack_w(const float* __restrict__ w, _Float16* __restrict__ wr,
                         int ngt, int cin, int xmode) {
    int total = ngt * 8192;
    for (int idx = blockIdx.x * blockDim.x + threadIdx.x; idx < total;
         idx += gridDim.x * blockDim.x) {
        int k = idx & 31;
        int m = (idx >> 5) & 255;
        int gt = idx >> 13;
        int chunk = gt / 9, tap = gt - chunk * 9;
        int bidx = m >> 4, i = m & 15;
        int g = bidx >> 2, hg = bidx & 3;
        int out = g * 64 + hg * 16 + i;
        int kg = chunk * 32 + k;
        int ci = xmode ? (kg < 64 ? kg + 1 : (kg == 64 ? 0 : -1))
                       : (kg < cin ? kg : -1);
        float v = (ci >= 0) ? w[(out * cin + ci) * 9 + tap] : 0.f;
        wr[idx] = (_Float16)v;
    }
}

// Fused conv3x3 -> 4 gates -> LSTM update. f16 MFMA implicit GEMM.
// Block: 256 thr (4 waves = 4 hid-groups), ONE image row x 64 cols (N=64), M=256.
// Wave tile M=64 x N=64 -> acc = 64 regs (vs 128 in R7) so 4 waves/SIMD fit:
// grid 64x16 = 1024 blocks = 4 blocks/CU = 16 waves/CU for latency hiding.
// Weights direct from L2 per tap (per-lane contiguous 16B; all 4 blocks/CU read
// the same 16KB/tap -> L1 reuse). Act tile (3 halo rows x 66 cols x 32ch) in LDS,
// 5-slot (80B) pixel stride -> 2-way bank access (free). 2 barriers per chunk.
template<int NCHUNK, int XCHUNK>
__global__ __launch_bounds__(256, 4) void lstm_mfma_kernel(
    const _Float16* __restrict__ srcA,    // chunks 0-1 (padded pixel-major h)
    const _Float16* __restrict__ srcB,    // chunks 2-3
    const float* __restrict__ xsrc,       // layer0 x_t (batch stride TSTEPS*HWSZ)
    _Float16* __restrict__ hpad,          // out h [B][66][66][64]
    float* __restrict__ cpix,             // in-place c [B][4096][64]
    const _Float16* __restrict__ wr,      // [NGT][256][32] dense f16
    const float* __restrict__ bias)       // [256]
{
    __shared__ __align__(16) _Float16 act[198 * 5 * 8];   // 198 px x 5 slots x 16B = 15.8 KB

    const int tid = threadIdx.x;
    const int lane = tid & 63;
    const int n = lane & 15, q = lane >> 4;
    const int hg = tid >> 6;                 // wave = hid group 0..3
    const int rb = blockIdx.x;               // image row 0..63
    const int b = blockIdx.y;

    floatx4 acc[4][4];
    #pragma unroll
    for (int g = 0; g < 4; ++g)
        #pragma unroll
        for (int i = 0; i < 4; ++i) acc[g][i] = (floatx4){0.f, 0.f, 0.f, 0.f};

    // stage chunk's act tile: 3 halo rows x 66 cols x 32 ch -> 792 16B units
    auto stage = [&](int chunk) {
        if (chunk == XCHUNK) {
            for (int t = tid; t < 792; t += 256) {
                int pix = t >> 2, sl = t & 3;
                int r = pix / 66, cs = pix - r * 66;
                half8 hv;
                #pragma unroll
                for (int j = 0; j < 8; ++j) hv[j] = (_Float16)0.f;
                if (sl == 0) {
                    int gy = rb - 1 + r, gx = cs - 1;
                    float v = 0.f;
                    if (gy >= 0 && gy < IMH && gx >= 0 && gx < IMW)
                        v = xsrc[(size_t)b * (TSTEPS * HWSZ) + gy * IMW + gx];
                    hv[0] = (_Float16)v;
                }
                *(half8*)&act[(pix * 5 + sl) * 8] = hv;
            }
        } else {
            const _Float16* buf = (chunk < 2) ? srcA : srcB;
            const int halfsel = chunk & 1;
            for (int t = tid; t < 792; t += 256) {
                int pix = t >> 2, sl = t & 3;
                int r = pix / 66, cs = pix - r * 66;
                // padded source row = (rb-1+r)+1 = rb+r ; padded col = cs
                const _Float16* g = buf
                    + ((size_t)(b * PADW + rb + r) * PADW + cs) * 64
                    + halfsel * 32 + sl * 8;
                *(intx4*)&act[(pix * 5 + sl) * 8] = *(const intx4*)g;
            }
        }
    };

    for (int chunk = 0; chunk < NCHUNK; ++chunk) {
        __syncthreads();                     // B1: prev chunk's act readers done
        stage(chunk);
        __syncthreads();                     // B2: act writes visible
        const _Float16* wbase = wr + (size_t)(chunk * 9) * 8192 + (hg * 16 + n) * 32 + q * 8;
        #pragma unroll
        for (int tap = 0; tap < 9; ++tap) {
            half8 wfr[4];
            #pragma unroll
            for (int g = 0; g < 4; ++g)
                wfr[g] = *(const half8*)(wbase + (size_t)tap * 8192 + g * 2048);
            const int dy = tap / 3, dx = tap - dy * 3;
            half8 bfr[4];
            #pragma unroll
            for (int ni = 0; ni < 4; ++ni) {
                int col = 16 * ni + n + dx;              // 0..65
                bfr[ni] = *(const half8*)&act[((dy * 66 + col) * 5 + q) * 8];
            }
            #pragma unroll
            for (int g = 0; g < 4; ++g)
                #pragma unroll
                for (int ni = 0; ni < 4; ++ni)
                    acc[g][ni] = __builtin_amdgcn_mfma_f32_16x16x32_f16(
                        wfr[g], bfr[ni], acc[g][ni], 0, 0, 0);
        }
    }

    // Epilogue: lane holds gates for h = hg*16+q*4+r, pixel row rb, col 16*ni+n
    const int hb = hg * 16 + q * 4;
    floatx4 bi = *(const floatx4*)&bias[hb];
    floatx4 bf = *(const floatx4*)&bias[64 + hb];
    floatx4 bo = *(const floatx4*)&bias[128 + hb];
    floatx4 bg = *(const floatx4*)&bias[192 + hb];
    #pragma unroll
    for (int ni = 0; ni < 4; ++ni) {
        int col = 16 * ni + n;
        size_t cidx = ((size_t)b * HWSZ + rb * IMW + col) * 64 + hb;
        floatx4 cold = *(const floatx4*)&cpix[cidx];
        floatx4 cnew;
        half4 hv;
        #pragma unroll
        for (int r = 0; r < 4; ++r) {
            float zi = acc[0][ni][r] + bi[r];
            float zf = acc[1][ni][r] + bf[r];
            float zo = acc[2][ni][r] + bo[r];
            float zg = acc[3][ni][r] + bg[r];
            float cn = fmaf(sigmoidf_(zf), cold[r], sigmoidf_(zi) * tanhf_(zg));
            cnew[r] = cn;
            hv[r] = (_Float16)(sigmoidf_(zo) * tanhf_(cn));
        }
        *(floatx4*)&cpix[cidx] = cnew;
        *(half4*)&hpad[((size_t)(b * PADW + rb + 1) * PADW + col + 1) * 64 + hb] = hv;
    }
}

__global__ void head_kernel(const _Float16* __restrict__ h1pad,
                            const float* __restrict__ wh,
                            const float* __restrict__ bh,
                            float* __restrict__ out) {
    int nn = blockIdx.x * blockDim.x + threadIdx.x;  // 0..65535
    int b = nn >> 12, pp = nn & 4095;
    int y = pp >> 6, xc = pp & 63;
    const _Float16* base = h1pad + ((size_t)(b * PADW + y + 1) * PADW + xc + 1) * 64;
    float s = bh[0];
    #pragma unroll
    for (int h0 = 0; h0 < 64; h0 += 8) {
        half8 hv = *(const half8*)&base[h0];
        #pragma unroll
        for (int j = 0; j < 8; ++j) s = fmaf((float)hv[j], wh[h0 + j], s);
    }
    out[nn] = fmaxf(s, 0.f);
}

extern "C" void kernel_launch(void* const* d_in, const int* in_sizes, int n_in,
                              void* d_out, int out_size, void* d_ws, size_t ws_size,
                              hipStream_t stream) {
    const float* x  = (const float*)d_in[0];
    const float* w0 = (const float*)d_in[1];
    const float* b0 = (const float*)d_in[2];
    const float* w1 = (const float*)d_in[3];
    const float* b1 = (const float*)d_in[4];
    const float* wh = (const float*)d_in[5];
    const float* bh = (const float*)d_in[6];
    float* out = (float*)d_out;

    const size_t HPAD = (size_t)BATCH * PADW * PADW * 64;  // 4,460,544 halves
    const size_t CBUF = (size_t)BATCH * HWSZ * 64;         // 4,194,304 floats
    _Float16* hp  = (_Float16*)d_ws;
    _Float16* h0a = hp;
    _Float16* h0b = hp + HPAD;
    _Float16* h1a = hp + 2 * HPAD;
    _Float16* h1b = hp + 3 * HPAD;
    float* cbase = (float*)(hp + 4 * HPAD);
    float* c0 = cbase;
    float* c1 = cbase + CBUF;
    _Float16* wr0 = (_Float16*)(cbase + 2 * CBUF);   // 27*8192 halves
    _Float16* wr1 = wr0 + (size_t)27 * 8192;         // 36*8192 halves

    // zero h buffers (borders must stay 0) and c buffers
    hipMemsetAsync(d_ws, 0, 4 * HPAD * sizeof(_Float16) + 2 * CBUF * sizeof(float), stream);
    repack_w<<<864, 256, 0, stream>>>(w0, wr0, 27, 65, 1);
    repack_w<<<1152, 256, 0, stream>>>(w1, wr1, 36, 128, 0);

    _Float16* h0buf[2] = {h0a, h0b};
    _Float16* h1buf[2] = {h1a, h1b};
    dim3 grid(64, BATCH), block(256);                // 1024 blocks = 4/CU
    for (int t = 0; t < TSTEPS; ++t) {
        int cur = t & 1, nxt = cur ^ 1;
        // layer0: chunks = [h0 ch0-31][h0 ch32-63][x + zeros]
        lstm_mfma_kernel<3, 2><<<grid, block, 0, stream>>>(
            h0buf[cur], (const _Float16*)nullptr, x + (size_t)t * HWSZ,
            h0buf[nxt], c0, wr0, b0);
        // layer1: chunks = [h0new 0-31][h0new 32-63][h1 0-31][h1 32-63]
        lstm_mfma_kernel<4, -1><<<grid, block, 0, stream>>>(
            h0buf[nxt], h1buf[cur], (const float*)nullptr,
            h1buf[nxt], c1, wr1, b1);
    }
    // t=15 wrote h1buf[0]
    head_kernel<<<256, 256, 0, stream>>>(h1buf[0], wh, bh, out);
}